// Round 3
// baseline (24.596 us; speedup 1.0000x reference)
//
#include <hip/hip_runtime.h>
#include <float.h>

#define INF_VAL 100000000.0f
#define NUM_CLASSES_K 80

// 4 lanes per location: lane group {l*4+c, c=0..3} splits the M boxes into 4
// chunks of ceil(M/4), each lane scans its chunk with strict-< (first
// occurrence within chunk), then a 2-step shfl_xor butterfly combines
// (cost, m) with lower-m tie-break => exact jnp.argmin first-occurrence
// semantics globally. Lane c==0 writes the outputs.
__global__ void fcos_targets_kernel(const float2* __restrict__ locations,
                                    const float2* __restrict__ size_ranges,
                                    const float* __restrict__ strides,
                                    const float4* __restrict__ bboxes,
                                    const int* __restrict__ classes,
                                    float* __restrict__ out_labels,
                                    float4* __restrict__ out_reg,
                                    int L, int M) {
    const int b = blockIdx.y;
    const int t = blockIdx.x * blockDim.x + threadIdx.x;
    const int l = t >> 2;
    const int c = t & 3;
    if (l >= L) return;  // all 4 lanes of a group share l -> uniform exit

    const float2 loc = locations[l];
    const float2 sr  = size_ranges[l];
    const float xs = loc.x, ys = loc.y;
    const float lo = sr.x,  hi = sr.y;

    const float4* boxes_b = bboxes + (size_t)b * M;

    const int CH    = (M + 3) >> 2;
    const int start = c * CH;
    const int end   = (start + CH < M) ? (start + CH) : M;

    float best  = FLT_MAX;
    int  best_m = start;
#pragma unroll 5
    for (int m = start; m < end; ++m) {
        const float4 bx = boxes_b[m];
        const float dl = xs - bx.x;
        const float dt = ys - bx.y;
        const float dr = bx.z - xs;
        const float db = bx.w - ys;
        const float mn = fminf(fminf(dl, dt), fminf(dr, db));
        const float mx = fmaxf(fmaxf(dl, dt), fmaxf(dr, db));
        const float area = (bx.z - bx.x) * (bx.w - bx.y);  // same expr as ref
        const bool ok = (mn > 0.0f) && (mx >= lo) && (mx <= hi);
        const float cost = ok ? area : INF_VAL;
        const bool better = cost < best;  // strict < => first occurrence
        best   = better ? cost : best;
        best_m = better ? m : best_m;
    }

    // Butterfly combine across the 4 chunks (xor by 1, 2 stays in-group).
    #pragma unroll
    for (int off = 1; off <= 2; off <<= 1) {
        const float oc = __shfl_xor(best, off);
        const int   om = __shfl_xor(best_m, off);
        if (oc < best || (oc == best && om < best_m)) {  // tie -> lower m
            best = oc;
            best_m = om;
        }
    }

    if (c == 0) {
        const float4 wb = boxes_b[best_m];
        const int    wc = classes[b * M + best_m];
        const float  stride = strides[l];

        const int label = (best >= INF_VAL) ? NUM_CLASSES_K : wc;

        float4 reg;
        reg.x = (xs - wb.x) / stride;
        reg.y = (ys - wb.y) / stride;
        reg.z = (wb.z - xs) / stride;
        reg.w = (wb.w - ys) / stride;

        out_labels[(size_t)b * L + l] = (float)label;
        out_reg[(size_t)b * L + l]    = reg;
    }
}

extern "C" void kernel_launch(void* const* d_in, const int* in_sizes, int n_in,
                              void* d_out, int out_size, void* d_ws, size_t ws_size,
                              hipStream_t stream) {
    const float2* locations   = (const float2*)d_in[0];
    const float2* size_ranges = (const float2*)d_in[1];
    const float*  strides     = (const float*)d_in[2];
    const float4* bboxes      = (const float4*)d_in[3];
    const int*    classes     = (const int*)d_in[4];

    const int L  = in_sizes[2];          // strides_per_loc: (L,)
    const int BM = in_sizes[4];          // gt_classes: (B, M)
    const int B  = out_size / (5 * L);   // out = B*L labels + B*L*4 reg
    const int M  = BM / B;

    float*  out        = (float*)d_out;
    float*  out_labels = out;                            // first B*L
    float4* out_reg    = (float4*)(out + (size_t)B * L); // then B*L*4

    const int threads_needed = L * 4;    // 4 lanes per location
    dim3 block(256);
    dim3 grid((threads_needed + 255) / 256, B);

    hipLaunchKernelGGL(fcos_targets_kernel, grid, block, 0, stream,
                       locations, size_ranges, strides, bboxes, classes,
                       out_labels, out_reg, L, M);
}

// Round 4
// 23.881 us; speedup vs baseline: 1.0299x; 1.0299x over previous
//
#include <hip/hip_runtime.h>
#include <float.h>

#define INF_VAL 100000000.0f
#define NUM_CLASSES_K 80

// One thread per (image b, location l). Boxes read via wave-uniform scalar
// loads (s_load_dwordx4). Per-wave SOI bounds (monotone along l -> lane 0 has
// min lo, lane 63 has max hi) prune boxes that provably cannot satisfy the
// size-of-interest test for ANY lane of the wave:
//   in-box  =>  max(w,h)/2 - eps <= max_reg < max(w,h) + eps
// so  max(w,h) > 2*hi+4  or  max(w,h) <= lo-4  =>  cost == INF for all lanes.
// Skip condition is computed from uniform values -> s_cbranch skips the body.
__global__ void fcos_targets_kernel(const float2* __restrict__ locations,
                                    const float2* __restrict__ size_ranges,
                                    const float* __restrict__ strides,
                                    const float4* __restrict__ bboxes,
                                    const int* __restrict__ classes,
                                    float* __restrict__ out_labels,
                                    float4* __restrict__ out_reg,
                                    int L, int M) {
    const int b = blockIdx.y;
    const int t = blockIdx.x * blockDim.x + threadIdx.x;
    const int l = (t < L) ? t : (L - 1);   // clamp: keep all 64 lanes active

    const float2 loc = locations[l];
    const float2 sr  = size_ranges[l];
    const float xs = loc.x, ys = loc.y;
    const float lo = sr.x,  hi = sr.y;

    // Wave-wide conservative SOI bounds (lo,hi monotone non-decreasing in l).
    const float lo_w = __shfl(lo, 0);
    const float hi_w = __shfl(hi, 63);
    const float up_thr = 2.0f * hi_w + 4.0f;   // skip if max(w,h) >  up_thr
    const float lo_thr = lo_w - 4.0f;          // skip if max(w,h) <= lo_thr

    const float4* boxes_b = bboxes + (size_t)b * M;

    // jnp.argmin first-occurrence semantics: strict <, init INF with best_m=0
    // (areas are < 2e5 << INF, so best==INF  <=>  no qualifying box).
    float best  = INF_VAL;
    int  best_m = 0;
    for (int m = 0; m < M; ++m) {
        const float4 bx = boxes_b[m];          // uniform -> s_load_dwordx4
        const float w = bx.z - bx.x;           // exact same expr as reference
        const float h = bx.w - bx.y;
        const float mwh = fmaxf(w, h);
        if (mwh <= up_thr && mwh > lo_thr) {   // wave-uniform prune
            const float dl = xs - bx.x;
            const float dt = ys - bx.y;
            const float dr = bx.z - xs;
            const float db = bx.w - ys;
            const float mn = fminf(fminf(dl, dt), fminf(dr, db));
            const float mx = fmaxf(fmaxf(dl, dt), fmaxf(dr, db));
            const float area = w * h;          // == (x2-x1)*(y2-y1)
            const bool ok = (mn > 0.0f) && (mx >= lo) && (mx <= hi);
            const bool better = ok && (area < best);  // strict < => first occ.
            best   = better ? area : best;
            best_m = better ? m : best_m;
        }
    }

    if (t < L) {
        const float4 wb = boxes_b[best_m];     // winner fetch (once)
        const int    wc = classes[b * M + best_m];
        const float  stride = strides[l];

        const int label = (best >= INF_VAL) ? NUM_CLASSES_K : wc;

        float4 reg;
        reg.x = (xs - wb.x) / stride;
        reg.y = (ys - wb.y) / stride;
        reg.z = (wb.z - xs) / stride;
        reg.w = (wb.w - ys) / stride;

        out_labels[(size_t)b * L + l] = (float)label;
        out_reg[(size_t)b * L + l]    = reg;
    }
}

extern "C" void kernel_launch(void* const* d_in, const int* in_sizes, int n_in,
                              void* d_out, int out_size, void* d_ws, size_t ws_size,
                              hipStream_t stream) {
    const float2* locations   = (const float2*)d_in[0];
    const float2* size_ranges = (const float2*)d_in[1];
    const float*  strides     = (const float*)d_in[2];
    const float4* bboxes      = (const float4*)d_in[3];
    const int*    classes     = (const int*)d_in[4];

    const int L  = in_sizes[2];          // strides_per_loc: (L,)
    const int BM = in_sizes[4];          // gt_classes: (B, M)
    const int B  = out_size / (5 * L);   // out = B*L labels + B*L*4 reg
    const int M  = BM / B;

    float*  out        = (float*)d_out;
    float*  out_labels = out;                            // first B*L
    float4* out_reg    = (float4*)(out + (size_t)B * L); // then B*L*4

    dim3 block(256);
    dim3 grid((L + 255) / 256, B);

    hipLaunchKernelGGL(fcos_targets_kernel, grid, block, 0, stream,
                       locations, size_ranges, strides, bboxes, classes,
                       out_labels, out_reg, L, M);
}

// Round 5
// 20.207 us; speedup vs baseline: 1.2172x; 1.1818x over previous
//
#include <hip/hip_runtime.h>
#include <float.h>

#define INF_VAL 100000000.0f
#define NUM_CLASSES_K 80

// One thread per (image b, location l).
// Phase 1 (per wave, per 64-box chunk): lane i tests box base+i's max(w,h)
// against wave-conservative SOI bounds -> __ballot -> uniform 64-bit mask.
//   in-box => max_reg in [max(w,h)/2 - eps, max(w,h) + eps), so a box can
//   qualify for SOME lane only if max(w,h) <= 2*hi_w + 4 and > lo_w - 4.
// Phase 2: while(mask) { m = ctz; ... } -- loop control pure SALU, box data
// via wave-uniform s_load_dwordx4, body only for surviving boxes (~16/100).
// Ascending-m scan + strict < == jnp.argmin first-occurrence. All-INF rows
// keep best_m = 0 -> reg computed from box 0, matching reference.
__global__ void fcos_targets_kernel(const float2* __restrict__ locations,
                                    const float2* __restrict__ size_ranges,
                                    const float* __restrict__ strides,
                                    const float4* __restrict__ bboxes,
                                    const int* __restrict__ classes,
                                    float* __restrict__ out_labels,
                                    float4* __restrict__ out_reg,
                                    int L, int M) {
    const int b = blockIdx.y;
    const int t = blockIdx.x * blockDim.x + threadIdx.x;
    const int l = (t < L) ? t : (L - 1);   // clamp: all 64 lanes stay active
    const int lane = threadIdx.x & 63;

    const float2 loc = locations[l];
    const float2 sr  = size_ranges[l];
    const float xs = loc.x, ys = loc.y;
    const float lo = sr.x,  hi = sr.y;

    // Wave-conservative SOI bounds (lo,hi monotone non-decreasing in l).
    const float lo_w = __shfl(lo, 0);
    const float hi_w = __shfl(hi, 63);
    const float up_thr = 2.0f * hi_w + 4.0f;
    const float lo_thr = lo_w - 4.0f;

    const float4* boxes_b = bboxes + (size_t)b * M;

    float best  = INF_VAL;
    int  best_m = 0;

    for (int base = 0; base < M; base += 64) {
        // ---- Phase 1: parallel prune -> ballot mask (uniform) ----
        const int mm = base + lane;
        bool pred = false;
        if (mm < M) {
            const float4 px = boxes_b[mm];       // coalesced vector load
            const float pw = px.z - px.x;
            const float ph = px.w - px.y;
            const float mwh = fmaxf(pw, ph);
            pred = (mwh <= up_thr) && (mwh > lo_thr);
        }
        unsigned long long mask = __ballot(pred);

        // ---- Phase 2: scalar-controlled scan of survivors ----
        while (mask) {
            const int m = base + (int)__builtin_ctzll(mask);
            mask &= (mask - 1);
            const float4 bx = boxes_b[m];        // uniform -> s_load_dwordx4
            const float dl = xs - bx.x;
            const float dt = ys - bx.y;
            const float dr = bx.z - xs;
            const float db = bx.w - ys;
            const float mn = fminf(fminf(dl, dt), fminf(dr, db));
            const float mx = fmaxf(fmaxf(dl, dt), fmaxf(dr, db));
            const float area = (bx.z - bx.x) * (bx.w - bx.y);  // same as ref
            const bool ok = (mn > 0.0f) && (mx >= lo) && (mx <= hi);
            const bool better = ok && (area < best);  // strict < => first occ
            best   = better ? area : best;
            best_m = better ? m : best_m;
        }
    }

    if (t < L) {
        const float4 wb = boxes_b[best_m];       // winner fetch (once)
        const int    wc = classes[b * M + best_m];
        const float  stride = strides[l];

        const int label = (best >= INF_VAL) ? NUM_CLASSES_K : wc;

        float4 reg;
        reg.x = (xs - wb.x) / stride;
        reg.y = (ys - wb.y) / stride;
        reg.z = (wb.z - xs) / stride;
        reg.w = (wb.w - ys) / stride;

        out_labels[(size_t)b * L + l] = (float)label;
        out_reg[(size_t)b * L + l]    = reg;
    }
}

extern "C" void kernel_launch(void* const* d_in, const int* in_sizes, int n_in,
                              void* d_out, int out_size, void* d_ws, size_t ws_size,
                              hipStream_t stream) {
    const float2* locations   = (const float2*)d_in[0];
    const float2* size_ranges = (const float2*)d_in[1];
    const float*  strides     = (const float*)d_in[2];
    const float4* bboxes      = (const float4*)d_in[3];
    const int*    classes     = (const int*)d_in[4];

    const int L  = in_sizes[2];          // strides_per_loc: (L,)
    const int BM = in_sizes[4];          // gt_classes: (B, M)
    const int B  = out_size / (5 * L);   // out = B*L labels + B*L*4 reg
    const int M  = BM / B;

    float*  out        = (float*)d_out;
    float*  out_labels = out;                            // first B*L
    float4* out_reg    = (float4*)(out + (size_t)B * L); // then B*L*4

    dim3 block(256);
    dim3 grid((L + 255) / 256, B);

    hipLaunchKernelGGL(fcos_targets_kernel, grid, block, 0, stream,
                       locations, size_ranges, strides, bboxes, classes,
                       out_labels, out_reg, L, M);
}

// Round 6
// 16.833 us; speedup vs baseline: 1.4612x; 1.2004x over previous
//
#include <hip/hip_runtime.h>
#include <float.h>

#define INF_VAL 100000000.0f
#define NUM_CLASSES_K 80

// One thread per (image b, location l).
// Phase 1: per 64-box chunk, lane i tests box base+i's max(w,h) against
// wave-conservative SOI bounds -> __ballot -> uniform survivor mask.
//   in-box => max_reg in [max(w,h)/2 - eps, max(w,h) + eps), eps ~ 4e-4,
//   so skip iff max(w,h) > 2*hi_w + 4 or max(w,h) <= lo_w - 4 (margin >> eps).
// Phase 2: batched scalar scan -- extract up to 4 survivor indices per outer
// iteration (pure SALU on the uniform mask), issue 4 INDEPENDENT
// s_load_dwordx4 back-to-back (amortizes SMEM latency; R5's one-at-a-time
// dependent chain was the regression), then process 4. Padding with a
// duplicate index is harmless under strict-< argmin.
// Ascending-m order + strict < == jnp.argmin first occurrence. All-INF rows
// keep best_m = 0 -> reg computed from box 0, matching reference.
__global__ void fcos_targets_kernel(const float2* __restrict__ locations,
                                    const float2* __restrict__ size_ranges,
                                    const float* __restrict__ strides,
                                    const float4* __restrict__ bboxes,
                                    const int* __restrict__ classes,
                                    float* __restrict__ out_labels,
                                    float4* __restrict__ out_reg,
                                    int L, int M) {
    const int b = blockIdx.y;
    const int t = blockIdx.x * blockDim.x + threadIdx.x;
    const int l = (t < L) ? t : (L - 1);   // clamp: all 64 lanes stay active
    const int lane = threadIdx.x & 63;

    const float2 loc = locations[l];
    const float2 sr  = size_ranges[l];
    const float xs = loc.x, ys = loc.y;
    const float lo = sr.x,  hi = sr.y;

    // Wave-conservative SOI bounds (lo,hi monotone non-decreasing in l).
    const float lo_w = __shfl(lo, 0);
    const float hi_w = __shfl(hi, 63);
    const float up_thr = 2.0f * hi_w + 4.0f;
    const float lo_thr = lo_w - 4.0f;

    const float4* boxes_b = bboxes + (size_t)b * M;

    float best  = INF_VAL;
    int  best_m = 0;

#define PROC(BX, MIDX)                                                       \
    {                                                                        \
        const float dl = xs - (BX).x;                                        \
        const float dt = ys - (BX).y;                                        \
        const float dr = (BX).z - xs;                                        \
        const float db = (BX).w - ys;                                        \
        const float mn = fminf(fminf(dl, dt), fminf(dr, db));                \
        const float mx = fmaxf(fmaxf(dl, dt), fmaxf(dr, db));                \
        const float area = ((BX).z - (BX).x) * ((BX).w - (BX).y);            \
        const bool ok = (mn > 0.0f) && (mx >= lo) && (mx <= hi);             \
        const bool better = ok && (area < best);                             \
        best   = better ? area : best;                                       \
        best_m = better ? (MIDX) : best_m;                                   \
    }

    for (int base = 0; base < M; base += 64) {
        // ---- Phase 1: parallel prune -> uniform ballot mask ----
        const int mm = base + lane;
        bool pred = false;
        if (mm < M) {
            const float4 px = boxes_b[mm];       // coalesced vector load
            const float mwh = fmaxf(px.z - px.x, px.w - px.y);
            pred = (mwh <= up_thr) && (mwh > lo_thr);
        }
        unsigned long long mask = __ballot(pred);

        // ---- Phase 2: 4-wide batched scalar scan of survivors ----
        while (mask) {
            int i0 = (int)__builtin_ctzll(mask); mask &= (mask - 1);
            int i1 = i0, i2 = i0, i3 = i0;
            if (mask) { i1 = (int)__builtin_ctzll(mask); mask &= (mask - 1); }
            if (mask) { i2 = (int)__builtin_ctzll(mask); mask &= (mask - 1); }
            if (mask) { i3 = (int)__builtin_ctzll(mask); mask &= (mask - 1); }
            // 4 independent wave-uniform loads -> s_load_dwordx4 x4 in flight
            const float4 b0 = boxes_b[base + i0];
            const float4 b1 = boxes_b[base + i1];
            const float4 b2 = boxes_b[base + i2];
            const float4 b3 = boxes_b[base + i3];
            PROC(b0, base + i0);
            PROC(b1, base + i1);   // duplicates harmless: strict < can't re-fire
            PROC(b2, base + i2);
            PROC(b3, base + i3);
        }
    }
#undef PROC

    if (t < L) {
        const float4 wb = boxes_b[best_m];       // winner fetch (once)
        const int    wc = classes[b * M + best_m];
        const float  stride = strides[l];

        const int label = (best >= INF_VAL) ? NUM_CLASSES_K : wc;

        float4 reg;
        reg.x = (xs - wb.x) / stride;
        reg.y = (ys - wb.y) / stride;
        reg.z = (wb.z - xs) / stride;
        reg.w = (wb.w - ys) / stride;

        out_labels[(size_t)b * L + l] = (float)label;
        out_reg[(size_t)b * L + l]    = reg;
    }
}

extern "C" void kernel_launch(void* const* d_in, const int* in_sizes, int n_in,
                              void* d_out, int out_size, void* d_ws, size_t ws_size,
                              hipStream_t stream) {
    const float2* locations   = (const float2*)d_in[0];
    const float2* size_ranges = (const float2*)d_in[1];
    const float*  strides     = (const float*)d_in[2];
    const float4* bboxes      = (const float4*)d_in[3];
    const int*    classes     = (const int*)d_in[4];

    const int L  = in_sizes[2];          // strides_per_loc: (L,)
    const int BM = in_sizes[4];          // gt_classes: (B, M)
    const int B  = out_size / (5 * L);   // out = B*L labels + B*L*4 reg
    const int M  = BM / B;

    float*  out        = (float*)d_out;
    float*  out_labels = out;                            // first B*L
    float4* out_reg    = (float4*)(out + (size_t)B * L); // then B*L*4

    dim3 block(256);
    dim3 grid((L + 255) / 256, B);

    hipLaunchKernelGGL(fcos_targets_kernel, grid, block, 0, stream,
                       locations, size_ranges, strides, bboxes, classes,
                       out_labels, out_reg, L, M);
}